// Round 1
// baseline (141.071 us; speedup 1.0000x reference)
//
#include <hip/hip_runtime.h>
#include <math.h>

#define NPTS 4096
#define NSMP 10

typedef float f32x2 __attribute__((ext_vector_type(2)));
typedef _Float16 half8 __attribute__((ext_vector_type(8)));
typedef float f32x16 __attribute__((ext_vector_type(16)));

// ---------------- prep: fuse (w1,b1,w2,b2) -> Wn[30][64] ([s*3+c][p]), bb[64] ----------
// out[p] = bb[p] + sum_{s,c} Wn[s*3+c][p] * pos[b,c,idx_s]  (no nonlinearity -> legal).
__global__ __launch_bounds__(256) void prep_kernel(
    const float* __restrict__ w1, const float* __restrict__ b1,
    const float* __restrict__ w2, const float* __restrict__ b2,
    float* __restrict__ wn, float* __restrict__ bb) {
  __shared__ float w1l[64 * 48];      // 12 KB, [o][k]
  __shared__ float w2t[64 * 64];      // 16 KB, transposed [o][p] (lane reads stride-1)
  __shared__ float b1l[64];
  __shared__ float part[4][30][64];   // 30 KB
  __shared__ float bpart[4][64];
  const int t = threadIdx.x, p = t & 63, grp = t >> 6, o0 = grp * 16;
  for (int idx = t; idx < 64 * 48; idx += 256) w1l[idx] = w1[idx];
  for (int idx = t; idx < 64 * 64; idx += 256) w2t[(idx & 63) * 64 + (idx >> 6)] = w2[idx];
  if (t < 64) b1l[t] = b1[t];
  __syncthreads();

  const int sg[16] = {0,2,4,6, 3,5,7,9, 1,3,5,7, 2,4,6,8};
  float w2r[16];
  #pragma unroll
  for (int oo = 0; oo < 16; ++oo) w2r[oo] = w2t[(o0 + oo) * 64 + p];
  float wloc[30];
  #pragma unroll
  for (int i = 0; i < 30; ++i) wloc[i] = 0.0f;
  #pragma unroll
  for (int g = 0; g < 4; ++g)
    #pragma unroll
    for (int i = 0; i < 2; ++i)
      #pragma unroll
      for (int j = 0; j < 2; ++j) {
        const int s = sg[g * 4 + i * 2 + j];
        #pragma unroll
        for (int c = 0; c < 3; ++c) {
          const int k = (c + 3 * g) * 4 + i * 2 + j;   // w1 flat index over (12,2,2)
          float wk = 0.0f;
          #pragma unroll
          for (int oo = 0; oo < 16; ++oo)
            wk = fmaf(w2r[oo], w1l[(o0 + oo) * 48 + k], wk);  // w1l read is broadcast
          wloc[s * 3 + c] += wk;
        }
      }
  #pragma unroll
  for (int i = 0; i < 30; ++i) part[grp][i][p] = wloc[i];
  float sb = 0.0f;
  #pragma unroll
  for (int oo = 0; oo < 16; ++oo) sb = fmaf(w2r[oo], b1l[o0 + oo], sb);
  bpart[grp][p] = sb;
  __syncthreads();
  const float* p0 = &part[0][0][0];
  for (int idx = t; idx < 30 * 64; idx += 256)
    wn[idx] = p0[idx] + p0[1920 + idx] + p0[3840 + idx] + p0[5760 + idx];
  if (t < 64) bb[t] = b2[t] + bpart[0][t] + bpart[1][t] + bpart[2][t] + bpart[3][t];
}

// ---------------- fused topk + mlp — MFMA-filter edition ------------------------------
// The f32-VALU distance filter (61% VALUBusy, MfmaUtil 0) is replaced by
// v_mfma_f32_32x32x16_f16: key[q][p] = -2*f16(q).P + |P|^2 packed as a K=8 dot
// (upper 8 k-lanes zeroed through a zero A-half).  B-side (points + |P|^2) is hi/lo
// fp16-split -> only error source is the fp16-rounded QUERY: |err| <= 2*2^-11*Pmax*
// sum|q_c|, absorbed by per-row slack 1.5e-3 + 0.012*sum|q_c| (Pmax<=6.1 covered).
// tau = exact 10th-smallest of 64 unit-mins (8 col-groups x 8 waves, 64 pts each):
// >=10 survivors guaranteed; slack adds ~2-9 extras on a ~11-15 base (cap 64 safe).
// Pass-2 recompute is bit-identical MFMA -> same keys.  f64 re-rank from EXACT f32
// coords (global, L2-resident) + identical epilogue -> output identical to R7.
// LDS 93.25 KB -> 1 block/CU, 16 waves (4/SIMD).  Grid 64x8 = 512 blocks = 2 rounds.
__global__ __launch_bounds__(1024, 4) void topk_kernel(const float* __restrict__ pos,
                                                       const float* __restrict__ wng,
                                                       const float* __restrict__ bbg,
                                                       float* __restrict__ out) {
  __shared__ half8 pts8[NPTS];        // 64 KB: [hX,lX,hY,lY,hZ,lZ,h_sq,l_sq] per point
  __shared__ float X[16 * 260];       // 16.25 KB: minbuf(4096) -> bufi(4096) -> trans
  __shared__ half8 a8[128];           // 2 KB: per query row {real 8 terms, 8 zeros}
  __shared__ float wl[30 * 64];       // 7.5 KB Wn
  __shared__ float bl[64];
  __shared__ float taub[64];
  __shared__ float slackb[64];
  __shared__ int   cnt[64];
  __shared__ int   nbrT[64][NSMP];    // 2.5 KB

  const int b = blockIdx.y, tid = threadIdx.x, lane = tid & 63, wv = tid >> 6;
  const float* pb = pos + (size_t)b * 3 * NPTS;
  const int nb = blockIdx.x * 64;

  // ---- staging: hi/lo fp16 split of points and |P|^2 ----
  for (int i = tid; i < NPTS; i += 1024) {
    float x = pb[i], y = pb[i + NPTS], z = pb[i + 2 * NPTS];
    float sq = fmaf(z, z, fmaf(y, y, x * x));
    _Float16 hx = (_Float16)x, hy = (_Float16)y, hz = (_Float16)z, hs = (_Float16)sq;
    _Float16 lx = (_Float16)(x - (float)hx);
    _Float16 ly = (_Float16)(y - (float)hy);
    _Float16 lz = (_Float16)(z - (float)hz);
    _Float16 ls = (_Float16)(sq - (float)hs);
    half8 v = {hx, lx, hy, ly, hz, lz, hs, ls};
    pts8[i] = v;
  }
  if (tid < 64) {
    float qx = pb[nb + tid], qy = pb[nb + tid + NPTS], qz = pb[nb + tid + 2 * NPTS];
    _Float16 ax = (_Float16)(-2.0f * (float)(_Float16)qx);   // -2*f16(q): exact in f16
    _Float16 ay = (_Float16)(-2.0f * (float)(_Float16)qy);
    _Float16 az = (_Float16)(-2.0f * (float)(_Float16)qz);
    _Float16 one = (_Float16)1.0f;
    half8 va = {ax, ax, ay, ay, az, az, one, one};
    half8 vz;
    #pragma unroll
    for (int j = 0; j < 8; ++j) vz[j] = (_Float16)0.0f;
    a8[2 * tid] = va;
    a8[2 * tid + 1] = vz;                                    // zero A-half -> k=8..15 dead
    slackb[tid] = 1.5e-3f + 0.012f * (fabsf(qx) + fabsf(qy) + fabsf(qz));
    cnt[tid] = 0;
    bl[tid] = bbg[tid];
  }
  for (int i = tid; i < 30 * 64; i += 1024) wl[i] = wng[i];
  __syncthreads();

  // wave geometry: qt = query-tile (32 rows), ws covers 512 points = 16 MFMA tiles
  const int qt = wv >> 3, ws = wv & 7, h = lane >> 5, c31 = lane & 31;
  const int base = ws * 512;
  const half8 af = a8[(qt * 32 + c31) * 2 + h];
  f32x16 zz;
  #pragma unroll
  for (int j = 0; j < 16; ++j) zz[j] = 0.0f;

  // ---- pass 1: MFMA keys, running min per C-reg ----
  float mreg[16];
  #pragma unroll
  for (int j = 0; j < 16; ++j) mreg[j] = INFINITY;
  #pragma unroll
  for (int t = 0; t < 16; ++t) {
    half8 bf = pts8[base + t * 32 + c31];
    f32x16 acc = __builtin_amdgcn_mfma_f32_32x32x16_f16(af, bf, zz, 0, 0, 0);
    #pragma unroll
    for (int j = 0; j < 16; ++j) mreg[j] = fminf(mreg[j], acc[j]);
  }
  // reduce 32 col-mins -> 8 unit-mins (groups of 4 cols); write minbuf[row][ws*8+g]
  #pragma unroll
  for (int j = 0; j < 16; ++j) {
    mreg[j] = fminf(mreg[j], __shfl_xor(mreg[j], 1));
    mreg[j] = fminf(mreg[j], __shfl_xor(mreg[j], 2));
  }
  if ((lane & 3) == 0) {
    const int g = (lane >> 2) & 7;
    #pragma unroll
    for (int j = 0; j < 16; ++j) {
      const int row = qt * 32 + (j & 3) + 8 * (j >> 2) + 4 * h;  // C-layout row
      X[row * 64 + ws * 8 + g] = mreg[j];
    }
  }
  __syncthreads();

  // ---- tau: MSB-first radix-select over the row's 64 unit-mins (rows 4wv..4wv+3) ----
  unsigned um[4];
  #pragma unroll
  for (int r = 0; r < 4; ++r) {
    float dm = X[(4 * wv + r) * 64 + lane];
    unsigned ub = __float_as_uint(dm);
    um[r] = (ub & 0x80000000u) ? ~ub : (ub | 0x80000000u);
  }
  unsigned pfx0 = 0u, pfx1 = 0u, pfx2 = 0u, pfx3 = 0u;
  #pragma unroll 1
  for (int bno = 31; bno >= 8; --bno) {
    const unsigned bit = 1u << bno, ones = bit - 1u;
    if (__popcll(__ballot(um[0] <= (pfx0 | ones))) < NSMP) pfx0 |= bit;
    if (__popcll(__ballot(um[1] <= (pfx1 | ones))) < NSMP) pfx1 |= bit;
    if (__popcll(__ballot(um[2] <= (pfx2 | ones))) < NSMP) pfx2 |= bit;
    if (__popcll(__ballot(um[3] <= (pfx3 | ones))) < NSMP) pfx3 |= bit;
  }
  float tx[4];
  #pragma unroll
  for (int r = 0; r < 4; ++r) {
    unsigned T = ((r == 0) ? pfx0 : (r == 1) ? pfx1 : (r == 2) ? pfx2 : pfx3) | 0xFFu;
    unsigned tb = (T & 0x80000000u) ? (T ^ 0x80000000u) : ~T;
    float tf = __uint_as_float(tb);
    tx[r] = __fadd_rn(__fadd_rn(tf, slackb[4 * wv + r]), __fmul_rn(fabsf(tf), 1e-5f));
  }
  if (lane == 0) {
    taub[4 * wv + 0] = tx[0]; taub[4 * wv + 1] = tx[1];
    taub[4 * wv + 2] = tx[2]; taub[4 * wv + 3] = tx[3];
  }
  __syncthreads();

  // ---- pass 2: bit-identical MFMA recompute, push survivors (block-level buffers) ----
  float tau16[16];
  #pragma unroll
  for (int j = 0; j < 16; ++j) tau16[j] = taub[qt * 32 + (j & 3) + 8 * (j >> 2) + 4 * h];
  int* bufi = (int*)X;
  #pragma unroll 2
  for (int t = 0; t < 16; ++t) {
    const int m0 = base + t * 32 + c31;
    half8 bf = pts8[m0];
    f32x16 acc = __builtin_amdgcn_mfma_f32_32x32x16_f16(af, bf, zz, 0, 0, 0);
    #pragma unroll
    for (int j = 0; j < 16; ++j) {
      if (acc[j] <= tau16[j]) {
        const int row = qt * 32 + (j & 3) + 8 * (j >> 2) + 4 * h;
        int ps = atomicAdd(&cnt[row], 1);
        if (ps < 64) bufi[row * 64 + ps] = m0;
      }
    }
  }
  __syncthreads();

  // ---- pass 3: f64 re-rank via readlane rank-count (exact f32 coords from global) ----
  int c[4], si[4], rank[4];
  double dd[4];
  int cmax = 0;
  #pragma unroll
  for (int r = 0; r < 4; ++r) {
    c[r] = __builtin_amdgcn_readfirstlane(cnt[4 * wv + r]);
    if (c[r] > 64) c[r] = 64;
    cmax = (c[r] > cmax) ? c[r] : cmax;
    rank[r] = 0;
  }
  #pragma unroll
  for (int r = 0; r < 4; ++r) {
    const int nq = nb + 4 * wv + r;
    float qxf = pb[nq], qyf = pb[nq + NPTS], qzf = pb[nq + 2 * NPTS];
    if (lane < c[r]) {
      si[r] = bufi[(4 * wv + r) * 64 + lane];
      float px = pb[si[r]], py = pb[si[r] + NPTS], pz = pb[si[r] + 2 * NPTS];
      double dqx = (double)qxf, dqy = (double)qyf, dqz = (double)qzf;
      double dpx = (double)px, dpy = (double)py, dpz = (double)pz;
      double dot = dqx * dpx + dqy * dpy + dqz * dpz;
      double sqn = dqx * dqx + dqy * dqy + dqz * dqz;
      double sqm = dpx * dpx + dpy * dpy + dpz * dpz;
      dd[r] = (sqn - 2.0 * dot) + sqm;             // self -> exactly 0.0
    } else { dd[r] = (double)INFINITY; si[r] = 0x7FFFFFFF; }
  }
  #pragma unroll 1
  for (int j = 0; j < cmax; ++j) {
    #pragma unroll
    for (int r = 0; r < 4; ++r) {
      int jlo = __builtin_amdgcn_readlane(__double2loint(dd[r]), j);
      int jhi = __builtin_amdgcn_readlane(__double2hiint(dd[r]), j);
      int ji  = __builtin_amdgcn_readlane(si[r], j);
      double jd = __hiloint2double(jhi, jlo);
      if (jd < dd[r] || (jd == dd[r] && ji < si[r])) ++rank[r];
    }
  }
  #pragma unroll
  for (int r = 0; r < 4; ++r)
    if (lane < c[r] && rank[r] < NSMP)
      nbrT[4 * wv + r][rank[r]] = si[r];
  __syncthreads();   // bufi reads done before trans overwrite (X aliased)

  // ---- epilogue: MLP acc then per-wave transpose slice (exact f32 coords) ----
  float* transF = &X[wv * 260];
  #pragma unroll 1
  for (int r = 0; r < 4; ++r) {
    float a = bl[lane];
    #pragma unroll
    for (int s = 0; s < NSMP; ++s) {
      const int id = nbrT[4 * wv + r][s];  // uniform -> broadcast ds_read
      float px = pb[id], py = pb[id + NPTS], pz = pb[id + 2 * NPTS];  // L2-hot
      a = fmaf(wl[(s * 3 + 0) * 64 + lane], px, a);
      a = fmaf(wl[(s * 3 + 1) * 64 + lane], py, a);
      a = fmaf(wl[(s * 3 + 2) * 64 + lane], pz, a);
    }
    transF[r * 65 + lane] = a;            // padded row -> conflict-free
  }
  __syncthreads();

  // coalesced store: thread (p = tid>>4, t16 = tid&15) writes n = nb + 4*t16 .. +3
  {
    int p = tid >> 4, t16 = tid & 15;
    float4 v;
    v.x = X[t16 * 260 + 0 * 65 + p];
    v.y = X[t16 * 260 + 1 * 65 + p];
    v.z = X[t16 * 260 + 2 * 65 + p];
    v.w = X[t16 * 260 + 3 * 65 + p];
    *(float4*)(out + ((size_t)b * 64 + p) * NPTS + nb + 4 * t16) = v;
  }
}

extern "C" void kernel_launch(void* const* d_in, const int* in_sizes, int n_in,
                              void* d_out, int out_size, void* d_ws, size_t ws_size,
                              hipStream_t stream) {
  (void)in_sizes; (void)n_in; (void)out_size; (void)ws_size;
  const float* pos = (const float*)d_in[0];
  const float* w1  = (const float*)d_in[1];
  const float* b1  = (const float*)d_in[2];
  const float* w2  = (const float*)d_in[3];
  const float* b2  = (const float*)d_in[4];
  float* out = (float*)d_out;

  // workspace: Wn (30*64 f32) then bb (64 f32)
  float* wn = (float*)d_ws;
  float* bb = (float*)((char*)d_ws + 30 * 64 * 4);

  prep_kernel<<<dim3(1), dim3(256), 0, stream>>>(w1, b1, w2, b2, wn, bb);
  topk_kernel<<<dim3(64, 8), dim3(1024), 0, stream>>>(pos, wn, bb, out);
}